// Round 11
// baseline (285.812 us; speedup 1.0000x reference)
//
#include <hip/hip_runtime.h>
#include <hip/hip_cooperative_groups.h>
#include <math.h>

namespace cg = cooperative_groups;

#define BN_EPS 1e-5f

typedef _Float16 half2v __attribute__((ext_vector_type(2)));
typedef _Float16 half8v __attribute__((ext_vector_type(8)));
typedef __fp16 fp16x8 __attribute__((ext_vector_type(8)));
typedef float floatx4 __attribute__((ext_vector_type(4)));

__device__ __forceinline__ float fdot2(half2v a, half2v b, float c) {
    return __builtin_amdgcn_fdot2(a, b, c, false);
}
__device__ __forceinline__ half2v cvt2(float a, float b) {
    return __builtin_bit_cast(half2v, __builtin_amdgcn_cvt_pkrtz(a, b));
}
__device__ __forceinline__ floatx4 mfma16(half8v a, half8v b, floatx4 c) {
    return __builtin_amdgcn_mfma_f32_16x16x32_f16(
        __builtin_bit_cast(fp16x8, a), __builtin_bit_cast(fp16x8, b), c, 0, 0, 0);
}

// ---------------------------------------------------------------------------
// Single cooperative kernel, 256 blocks x 512 threads (1 block/CU, all
// co-resident). LDS: one 78080 B arena, re-viewed per phase.
// Phase 1: fused3 GEMMs, 192 jobs of 64m x 64n (verified R8 MFMA structure).
// Phase 2: h2 MFMA (jobs 0..127) + sim triangle tiles (jobs 128..263) — R10
//          bodies unchanged.
// Phase 3: head (blocks 0..63, one wave per row).
// __threadfence() before each grid.sync(): device-scope release (L2 wb/inv)
// — required across XCDs since per-XCD L2 may hold stale lines from the
// previous graph iteration.
// ---------------------------------------------------------------------------
__global__ __launch_bounds__(512) void mega_kernel(
    const float* __restrict__ x,
    const float* __restrict__ W1, const float* __restrict__ b1,
    const float* __restrict__ g, const float* __restrict__ be,
    const float* __restrict__ mu, const float* __restrict__ va,
    const float* __restrict__ Wa, const float* __restrict__ bs1,
    const float* __restrict__ Wb,
    const float* __restrict__ W2, const float* __restrict__ b2,
    const float* __restrict__ W3, const float* __restrict__ b3,
    const float* __restrict__ ws2, const float* __restrict__ bs2,
    _Float16* __restrict__ h16, _Float16* __restrict__ A16,
    _Float16* __restrict__ C16, float* __restrict__ h2o,
    float* __restrict__ out)
{
    __shared__ __align__(16) char smem[78080];
    const int bid = blockIdx.x;
    const int t   = threadIdx.x;
    cg::grid_group grid = cg::this_grid();

    // ======================= phase 1: fused3 ===============================
    if (bid < 192) {
        _Float16* Xs = (_Float16*)smem;          // 64 x 264
        _Float16* Ws = Xs + 64 * 264;            // 64 x 264
        const int z   = bid / 64;
        const int rem = bid % 64;
        const int m0 = (rem >> 3) * 64;
        const int n0 = (rem & 7) * 64;
        const float* __restrict__ Wp = (z == 0) ? W1 : (z == 1 ? Wa : Wb);

        #pragma unroll
        for (int i = 0; i < 8; ++i) {
            const int c = t + i * 512;
            const int row = c >> 6;
            const int c4  = c & 63;
            const float4 v = *(const float4*)&x[(m0 + row) * 256 + c4 * 4];
            *(half2v*)&Xs[row * 264 + c4 * 4 + 0] = cvt2(v.x, v.y);
            *(half2v*)&Xs[row * 264 + c4 * 4 + 2] = cvt2(v.z, v.w);
        }
        #pragma unroll
        for (int i = 0; i < 8; ++i) {
            const int c = t + i * 512;
            const int row = c >> 6;
            const int c4  = c & 63;
            const float4 v = *(const float4*)&Wp[(n0 + row) * 256 + c4 * 4];
            *(half2v*)&Ws[row * 264 + c4 * 4 + 0] = cvt2(v.x, v.y);
            *(half2v*)&Ws[row * 264 + c4 * 4 + 2] = cvt2(v.z, v.w);
        }
        __syncthreads();

        const int wave = t >> 6;
        const int lane = t & 63;
        const int wy = wave >> 2, wx = wave & 3;   // 2 x 4 waves over 64m x 64n
        const int lrow = lane & 15;
        const int quad = lane >> 4;
        const int kq = quad * 8;

        floatx4 acc[2] = {{0.f, 0.f, 0.f, 0.f}, {0.f, 0.f, 0.f, 0.f}};
        #pragma unroll
        for (int kc = 0; kc < 256; kc += 32) {
            const half8v a0 = *(const half8v*)&Xs[(wy * 32 + lrow) * 264 + kc + kq];
            const half8v a1 = *(const half8v*)&Xs[(wy * 32 + 16 + lrow) * 264 + kc + kq];
            const half8v b0 = *(const half8v*)&Ws[(wx * 16 + lrow) * 264 + kc + kq];
            acc[0] = mfma16(a0, b0, acc[0]);
            acc[1] = mfma16(a1, b0, acc[1]);
        }

        const int n = n0 + wx * 16 + lrow;
        float scale, off;
        if (z == 0) {
            const float s = g[n] * rsqrtf(va[n] + BN_EPS);
            scale = s;
            off = (b1[n] - mu[n]) * s + be[n];
        } else if (z == 1) {
            scale = 1.f;
            off = bs1[n];
        } else {
            scale = 1.f;
            off = 0.f;
        }
        _Float16* __restrict__ dst = (z == 0) ? h16 : (z == 1 ? A16 : C16);
        #pragma unroll
        for (int mi = 0; mi < 2; ++mi) {
            #pragma unroll
            for (int r = 0; r < 4; ++r) {
                const int m = m0 + wy * 32 + mi * 16 + quad * 4 + r;
                float v = acc[mi][r] * scale + off;
                if (z == 0) v = fmaxf(v, 0.f);
                dst[m * 512 + n] = (_Float16)v;
            }
        }
    }

    __threadfence();
    grid.sync();

    // ======================= phase 2: h2 + sim =============================
    float* __restrict__ S = out + 10240;
    for (int job = bid; job < 264; job += 256) {
        __syncthreads();
        if (job < 128) {
            // ---- h2 = relu(h16 @ W2^T + b2), 32m x 32n, k-split 2 ----
            _Float16* Xs = (_Float16*)smem;            // 32 x 520
            _Float16* Ws = Xs + 32 * 520;              // 32 x 520
            float*    Ph = (float*)(smem + 66560);     // 32 x 33

            const int n0 = (job & 7) * 32;
            const int m0 = (job >> 3) * 32;

            #pragma unroll
            for (int i = 0; i < 4; ++i) {
                const int c = t + i * 512;
                const int row = c >> 6;
                const int c8  = c & 63;
                const float4 v = *(const float4*)&h16[(m0 + row) * 512 + c8 * 8];
                *(half8v*)&Xs[row * 520 + c8 * 8] = __builtin_bit_cast(half8v, v);
            }
            #pragma unroll
            for (int i = 0; i < 4; ++i) {
                const int c = t + i * 512;
                const int row = c >> 6;
                const int c8  = c & 63;
                const float4 v0 = *(const float4*)&W2[(n0 + row) * 512 + c8 * 8];
                const float4 v1 = *(const float4*)&W2[(n0 + row) * 512 + c8 * 8 + 4];
                _Float16* d = &Ws[row * 520 + c8 * 8];
                *(half2v*)(d + 0) = cvt2(v0.x, v0.y);
                *(half2v*)(d + 2) = cvt2(v0.z, v0.w);
                *(half2v*)(d + 4) = cvt2(v1.x, v1.y);
                *(half2v*)(d + 6) = cvt2(v1.z, v1.w);
            }
            __syncthreads();

            const int wave = t >> 6;
            const int lane = t & 63;
            const int gk = wave >> 2;
            const int wl = wave & 3;
            const int wy = wl >> 1, wx = wl & 1;
            const int lrow = lane & 15;
            const int quad = lane >> 4;
            const int kq = quad * 8;
            const int kb = gk * 256;

            floatx4 acc = {0.f, 0.f, 0.f, 0.f};
            #pragma unroll
            for (int kc = 0; kc < 256; kc += 32) {
                const half8v a = *(const half8v*)&Xs[(wy * 16 + lrow) * 520 + kb + kc + kq];
                const half8v b = *(const half8v*)&Ws[(wx * 16 + lrow) * 520 + kb + kc + kq];
                acc = mfma16(a, b, acc);
            }

            if (gk == 1) {
                #pragma unroll
                for (int r = 0; r < 4; ++r)
                    Ph[(wy * 16 + quad * 4 + r) * 33 + wx * 16 + lrow] = acc[r];
            }
            __syncthreads();
            if (gk == 0) {
                const int n = n0 + wx * 16 + lrow;
                const float bb = b2[n];
                #pragma unroll
                for (int r = 0; r < 4; ++r) {
                    const int ml = wy * 16 + quad * 4 + r;
                    h2o[(m0 + ml) * 256 + n] =
                        fmaxf(acc[r] + Ph[ml * 33 + wx * 16 + lrow] + bb, 0.f);
                }
            }
        } else {
            // ---- sim triangle tile 32x32 (it<=jt), 2x2/thread, k-split 2 ----
            _Float16* Rs = (_Float16*)smem;                 // 32 x 536
            _Float16* Qs = Rs + 32 * 536;                   // 32 x 536
            half2v*  wsh = (half2v*)(smem + 68608);         // 256 half2
            float*   Psf = (float*)(smem + 68608 + 1024);   // 32 x 33
            float*   Tt  = Psf + 32 * 33;                   // 32 x 33

            const int b = job - 128;
            int jt = 0;
            while ((jt + 1) * (jt + 2) / 2 <= b) ++jt;
            const int it = b - jt * (jt + 1) / 2;
            const int r0 = it * 32, q0 = jt * 32;
            const bool diag = (it == jt);

            const int gk = t >> 8;
            const int tl = t & 255;
            const int tx = tl & 15, ty = tl >> 4;

            if (t < 256) {
                half2v w;
                w.x = (_Float16)ws2[2 * t];
                w.y = (_Float16)ws2[2 * t + 1];
                wsh[t] = w;
            }
            #pragma unroll
            for (int i = 0; i < 4; ++i) {
                const int c = t + i * 512;
                const int row = c >> 6;
                const int c8  = c & 63;
                const float4 vr = *(const float4*)&A16[(r0 + row) * 512 + c8 * 8];
                const float4 vq = *(const float4*)&C16[(q0 + row) * 512 + c8 * 8];
                *(half8v*)&Rs[row * 536 + c8 * 8] = __builtin_bit_cast(half8v, vr);
                *(half8v*)&Qs[row * 536 + c8 * 8] = __builtin_bit_cast(half8v, vq);
            }
            __syncthreads();

            const int cb = gk * 32;
            const half8v* rp0 = (const half8v*)&Rs[(ty * 2 + 0) * 536];
            const half8v* rp1 = (const half8v*)&Rs[(ty * 2 + 1) * 536];
            const half8v* qp0 = (const half8v*)&Qs[(tx * 2 + 0) * 536];
            const half8v* qp1 = (const half8v*)&Qs[(tx * 2 + 1) * 536];
            const half8v* wp8 = (const half8v*)wsh;
            const half2v z2 = {(_Float16)0, (_Float16)0};

            float a00 = 0.f, a01 = 0.f, a10 = 0.f, a11 = 0.f;
            #pragma unroll 4
            for (int c = 0; c < 32; ++c) {
                const half8v r0c = rp0[cb + c];
                const half8v r1c = rp1[cb + c];
                const half8v q0c = qp0[cb + c];
                const half8v q1c = qp1[cb + c];
                const half8v wc  = wp8[cb + c];
                #pragma unroll
                for (int s = 0; s < 4; ++s) {
                    half2v r0s, r1s, q0s, q1s, wss;
                    switch (s) {
                    case 0: r0s = __builtin_shufflevector(r0c, r0c, 0, 1);
                            r1s = __builtin_shufflevector(r1c, r1c, 0, 1);
                            q0s = __builtin_shufflevector(q0c, q0c, 0, 1);
                            q1s = __builtin_shufflevector(q1c, q1c, 0, 1);
                            wss = __builtin_shufflevector(wc, wc, 0, 1); break;
                    case 1: r0s = __builtin_shufflevector(r0c, r0c, 2, 3);
                            r1s = __builtin_shufflevector(r1c, r1c, 2, 3);
                            q0s = __builtin_shufflevector(q0c, q0c, 2, 3);
                            q1s = __builtin_shufflevector(q1c, q1c, 2, 3);
                            wss = __builtin_shufflevector(wc, wc, 2, 3); break;
                    case 2: r0s = __builtin_shufflevector(r0c, r0c, 4, 5);
                            r1s = __builtin_shufflevector(r1c, r1c, 4, 5);
                            q0s = __builtin_shufflevector(q0c, q0c, 4, 5);
                            q1s = __builtin_shufflevector(q1c, q1c, 4, 5);
                            wss = __builtin_shufflevector(wc, wc, 4, 5); break;
                    default: r0s = __builtin_shufflevector(r0c, r0c, 6, 7);
                            r1s = __builtin_shufflevector(r1c, r1c, 6, 7);
                            q0s = __builtin_shufflevector(q0c, q0c, 6, 7);
                            q1s = __builtin_shufflevector(q1c, q1c, 6, 7);
                            wss = __builtin_shufflevector(wc, wc, 6, 7); break;
                    }
                    a00 = fdot2(__builtin_elementwise_max(r0s + q0s, z2), wss, a00);
                    a01 = fdot2(__builtin_elementwise_max(r0s + q1s, z2), wss, a01);
                    a10 = fdot2(__builtin_elementwise_max(r1s + q0s, z2), wss, a10);
                    a11 = fdot2(__builtin_elementwise_max(r1s + q1s, z2), wss, a11);
                }
            }

            if (gk == 1) {
                Psf[(ty * 2 + 0) * 33 + tx * 2 + 0] = a00;
                Psf[(ty * 2 + 0) * 33 + tx * 2 + 1] = a01;
                Psf[(ty * 2 + 1) * 33 + tx * 2 + 0] = a10;
                Psf[(ty * 2 + 1) * 33 + tx * 2 + 1] = a11;
            }
            __syncthreads();

            if (gk == 0) {
                const float bsv = bs2[0];
                float v[2][2];
                v[0][0] = a00 + Psf[(ty * 2 + 0) * 33 + tx * 2 + 0];
                v[0][1] = a01 + Psf[(ty * 2 + 0) * 33 + tx * 2 + 1];
                v[1][0] = a10 + Psf[(ty * 2 + 1) * 33 + tx * 2 + 0];
                v[1][1] = a11 + Psf[(ty * 2 + 1) * 33 + tx * 2 + 1];
                #pragma unroll
                for (int di = 0; di < 2; ++di)
                    #pragma unroll
                    for (int dj = 0; dj < 2; ++dj) {
                        v[di][dj] = 1.f / (1.f + __expf(-(v[di][dj] + bsv)));
                        Tt[(ty * 2 + di) * 33 + tx * 2 + dj] = v[di][dj];
                    }
                if (!diag) {
                    #pragma unroll
                    for (int di = 0; di < 2; ++di)
                        *(float2*)&S[(r0 + ty * 2 + di) * 512 + q0 + tx * 2] =
                            make_float2(v[di][0], v[di][1]);
                }
            }
            __syncthreads();

            if (gk == 0) {
                if (diag) {
                    #pragma unroll
                    for (int di = 0; di < 2; ++di)
                        #pragma unroll
                        for (int dj = 0; dj < 2; ++dj) {
                            const int rl = ty * 2 + di, ql = tx * 2 + dj;
                            const float o = rl < ql ? Tt[rl * 33 + ql]
                                          : (rl > ql ? Tt[ql * 33 + rl] : 0.f);
                            S[(r0 + rl) * 512 + q0 + ql] = o;
                        }
                } else {
                    #pragma unroll
                    for (int di = 0; di < 2; ++di)
                        #pragma unroll
                        for (int dj = 0; dj < 2; ++dj)
                            S[(q0 + ty * 2 + di) * 512 + r0 + tx * 2 + dj] =
                                Tt[(tx * 2 + dj) * 33 + ty * 2 + di];
                }
            }
        }
    }

    __threadfence();
    grid.sync();

    // ======================= phase 3: head =================================
    if (bid < 64) {
        const int lane = t & 63;
        const int r = bid * 8 + (t >> 6);

        float p[10];
        #pragma unroll
        for (int q = 0; q < 10; ++q) p[q] = 0.f;
        #pragma unroll
        for (int kk = 0; kk < 4; ++kk) {
            const int k = lane + kk * 64;
            const float hv = h2o[r * 256 + k];
            #pragma unroll
            for (int q = 0; q < 10; ++q)
                p[q] = fmaf(hv, W3[q * 256 + k], p[q]);
        }
        #pragma unroll
        for (int q = 0; q < 10; ++q) {
            #pragma unroll
            for (int off = 32; off > 0; off >>= 1)
                p[q] += __shfl_down(p[q], off);
        }
        if (lane == 0) {
            float s[10], m = -1e30f;
            #pragma unroll
            for (int q = 0; q < 10; ++q) { s[q] = p[q] + b3[q]; m = fmaxf(m, s[q]); }
            float e[10], sum = 0.f;
            #pragma unroll
            for (int q = 0; q < 10; ++q) { e[q] = __expf(s[q] - m); sum += e[q]; }
            const float inv = 1.f / sum;
            #pragma unroll
            for (int q = 0; q < 10; ++q) {
                out[r * 10 + q] = e[q] * inv;
                out[5120 + r * 10 + q] = s[q];
            }
        }
    }
}

extern "C" void kernel_launch(void* const* d_in, const int* in_sizes, int n_in,
                              void* d_out, int out_size, void* d_ws, size_t ws_size,
                              hipStream_t stream)
{
    const float* x   = (const float*)d_in[0];
    const float* W1  = (const float*)d_in[1];
    const float* b1  = (const float*)d_in[2];
    const float* g   = (const float*)d_in[3];
    const float* be  = (const float*)d_in[4];
    const float* mu  = (const float*)d_in[5];
    const float* va  = (const float*)d_in[6];
    const float* W2  = (const float*)d_in[7];
    const float* b2  = (const float*)d_in[8];
    const float* W3  = (const float*)d_in[9];
    const float* b3  = (const float*)d_in[10];
    const float* Wa  = (const float*)d_in[11];
    const float* Wb  = (const float*)d_in[12];
    const float* bs1 = (const float*)d_in[13];
    const float* ws2 = (const float*)d_in[14];
    const float* bs2 = (const float*)d_in[15];

    float* out = (float*)d_out;
    _Float16* h16 = (_Float16*)d_ws;               // 512*512 f16
    float* h2 = (float*)(h16 + 512 * 512);         // 512*256 f32
    _Float16* A16 = (_Float16*)(h2 + 512 * 256);   // 512*512 f16
    _Float16* C16 = A16 + 512 * 512;               // 512*512 f16

    void* args[] = {
        (void*)&x, (void*)&W1, (void*)&b1, (void*)&g, (void*)&be,
        (void*)&mu, (void*)&va, (void*)&Wa, (void*)&bs1, (void*)&Wb,
        (void*)&W2, (void*)&b2, (void*)&W3, (void*)&b3,
        (void*)&ws2, (void*)&bs2,
        (void*)&h16, (void*)&A16, (void*)&C16, (void*)&h2, (void*)&out
    };
    hipLaunchCooperativeKernel((const void*)mega_kernel, dim3(256), dim3(512),
                               args, 0, stream);
}

// Round 12
// 101.596 us; speedup vs baseline: 2.8132x; 2.8132x over previous
//
#include <hip/hip_runtime.h>
#include <math.h>

#define BN_EPS 1e-5f

typedef _Float16 half2v __attribute__((ext_vector_type(2)));
typedef _Float16 half8v __attribute__((ext_vector_type(8)));
typedef __fp16 fp16x8 __attribute__((ext_vector_type(8)));
typedef float floatx4 __attribute__((ext_vector_type(4)));

__device__ __forceinline__ float fdot2(half2v a, half2v b, float c) {
    return __builtin_amdgcn_fdot2(a, b, c, false);
}
__device__ __forceinline__ half2v cvt2(float a, float b) {
    return __builtin_bit_cast(half2v, __builtin_amdgcn_cvt_pkrtz(a, b));
}
__device__ __forceinline__ floatx4 mfma16(half8v a, half8v b, floatx4 c) {
    return __builtin_amdgcn_mfma_f32_16x16x32_f16(
        __builtin_bit_cast(fp16x8, a), __builtin_bit_cast(fp16x8, b), c, 0, 0, 0);
}

// ---------------------------------------------------------------------------
// fused3 (MFMA): z=0: h16=f16(relu(BN(x@W1^T+b1))); z=1: A16=f16(x@Wa^T+bs1);
// z=2: C16=f16(x@Wb^T). M=512,N=512,K=256. Verified R8/R9.
// ---------------------------------------------------------------------------
__global__ __launch_bounds__(256) void fused3_mfma(
    const float* __restrict__ x,
    const float* __restrict__ W1, const float* __restrict__ b1,
    const float* __restrict__ g, const float* __restrict__ be,
    const float* __restrict__ mu, const float* __restrict__ va,
    const float* __restrict__ Wa, const float* __restrict__ bs1,
    const float* __restrict__ Wb,
    _Float16* __restrict__ h16, _Float16* __restrict__ A16,
    _Float16* __restrict__ C16)
{
    __shared__ _Float16 Xs[64][264];
    __shared__ _Float16 Ws[32][264];

    const int t  = threadIdx.x;
    const int n0 = blockIdx.x * 32;
    const int m0 = blockIdx.y * 64;
    const int z  = blockIdx.z;
    const float* __restrict__ Wp = (z == 0) ? W1 : (z == 1 ? Wa : Wb);

    #pragma unroll
    for (int i = 0; i < 16; ++i) {
        const int cidx = t + i * 256;
        const int row = cidx >> 6;
        const int c4  = cidx & 63;
        const float4 v = *(const float4*)&x[(m0 + row) * 256 + c4 * 4];
        *(half2v*)&Xs[row][c4 * 4 + 0] = cvt2(v.x, v.y);
        *(half2v*)&Xs[row][c4 * 4 + 2] = cvt2(v.z, v.w);
    }
    #pragma unroll
    for (int i = 0; i < 8; ++i) {
        const int cidx = t + i * 256;
        const int row = cidx >> 6;
        const int c4  = cidx & 63;
        const float4 v = *(const float4*)&Wp[(n0 + row) * 256 + c4 * 4];
        *(half2v*)&Ws[row][c4 * 4 + 0] = cvt2(v.x, v.y);
        *(half2v*)&Ws[row][c4 * 4 + 2] = cvt2(v.z, v.w);
    }
    __syncthreads();

    const int wave = t >> 6;
    const int lane = t & 63;
    const int wy = wave >> 1, wx = wave & 1;
    const int lrow = lane & 15;
    const int quad = lane >> 4;
    const int kq = quad * 8;

    floatx4 acc[2] = {{0.f, 0.f, 0.f, 0.f}, {0.f, 0.f, 0.f, 0.f}};

    #pragma unroll
    for (int kc = 0; kc < 256; kc += 32) {
        const half8v a0 = *(const half8v*)&Xs[wy * 32 + lrow][kc + kq];
        const half8v a1 = *(const half8v*)&Xs[wy * 32 + 16 + lrow][kc + kq];
        const half8v b0 = *(const half8v*)&Ws[wx * 16 + lrow][kc + kq];
        acc[0] = mfma16(a0, b0, acc[0]);
        acc[1] = mfma16(a1, b0, acc[1]);
    }

    const int n = n0 + wx * 16 + lrow;
    float scale, off;
    if (z == 0) {
        const float s = g[n] * rsqrtf(va[n] + BN_EPS);
        scale = s;
        off = (b1[n] - mu[n]) * s + be[n];
    } else if (z == 1) {
        scale = 1.f;
        off = bs1[n];
    } else {
        scale = 1.f;
        off = 0.f;
    }
    _Float16* __restrict__ dst = (z == 0) ? h16 : (z == 1 ? A16 : C16);
    #pragma unroll
    for (int mi = 0; mi < 2; ++mi) {
        #pragma unroll
        for (int r = 0; r < 4; ++r) {
            const int m = m0 + wy * 32 + mi * 16 + quad * 4 + r;
            float v = acc[mi][r] * scale + off;
            if (z == 0) v = fmaxf(v, 0.f);
            dst[m * 512 + n] = (_Float16)v;
        }
    }
}

// ---------------------------------------------------------------------------
// h2 (MFMA) = relu(h16 @ W2^T + b2) fp32. M=512,N=256,K=512. Verified R9.
// ---------------------------------------------------------------------------
__global__ __launch_bounds__(256) void h2_mfma(
    const _Float16* __restrict__ h16, const float* __restrict__ W2,
    const float* __restrict__ b2, float* __restrict__ h2o)
{
    __shared__ _Float16 Xs[32][520];
    __shared__ _Float16 Ws[32][520];

    const int t  = threadIdx.x;
    const int n0 = blockIdx.x * 32;
    const int m0 = blockIdx.y * 32;

    #pragma unroll
    for (int i = 0; i < 8; ++i) {
        const int cidx = t + i * 256;
        const int row = cidx >> 6;
        const int c8  = cidx & 63;
        const float4 v = *(const float4*)&h16[(m0 + row) * 512 + c8 * 8];
        *(half8v*)&Xs[row][c8 * 8] = __builtin_bit_cast(half8v, v);
    }
    #pragma unroll
    for (int i = 0; i < 8; ++i) {
        const int cidx = t + i * 256;
        const int row = cidx >> 6;
        const int c8  = cidx & 63;
        const float4 v0 = *(const float4*)&W2[(n0 + row) * 512 + c8 * 8];
        const float4 v1 = *(const float4*)&W2[(n0 + row) * 512 + c8 * 8 + 4];
        *(half2v*)&Ws[row][c8 * 8 + 0] = cvt2(v0.x, v0.y);
        *(half2v*)&Ws[row][c8 * 8 + 2] = cvt2(v0.z, v0.w);
        *(half2v*)&Ws[row][c8 * 8 + 4] = cvt2(v1.x, v1.y);
        *(half2v*)&Ws[row][c8 * 8 + 6] = cvt2(v1.z, v1.w);
    }
    __syncthreads();

    const int wave = t >> 6;
    const int lane = t & 63;
    const int wy = wave >> 1, wx = wave & 1;
    const int lrow = lane & 15;
    const int quad = lane >> 4;
    const int kq = quad * 8;

    floatx4 acc = {0.f, 0.f, 0.f, 0.f};
    #pragma unroll
    for (int kc = 0; kc < 512; kc += 32) {
        const half8v a = *(const half8v*)&Xs[wy * 16 + lrow][kc + kq];
        const half8v b = *(const half8v*)&Ws[wx * 16 + lrow][kc + kq];
        acc = mfma16(a, b, acc);
    }

    const int n = n0 + wx * 16 + lrow;
    const float bb = b2[n];
    #pragma unroll
    for (int r = 0; r < 4; ++r) {
        const int m = m0 + wy * 16 + quad * 4 + r;
        h2o[m * 256 + n] = fmaxf(acc[r] + bb, 0.f);
    }
}

// ---------------------------------------------------------------------------
// tail: blocks 0..527 = sim triangle tiles 16x16 (it<=jt);
// blocks 528..655 = head (4 rows each). 256 threads. Verified R9.
// ---------------------------------------------------------------------------
__global__ __launch_bounds__(256) void tail_kernel(
    const float* __restrict__ h2, const float* __restrict__ W3,
    const float* __restrict__ b3,
    const _Float16* __restrict__ A16, const _Float16* __restrict__ C16,
    const float* __restrict__ ws2, const float* __restrict__ bs2,
    float* __restrict__ out)
{
    __shared__ _Float16 Rs[16][520];
    __shared__ _Float16 Qs[16][520];
    __shared__ half2v wsh[256];
    __shared__ float Tt[16][17];

    const int bid = blockIdx.x;
    const int t   = threadIdx.x;

    if (bid >= 528) {
        const int lane = t & 63;
        const int r = (bid - 528) * 4 + (t >> 6);

        float p[10];
        #pragma unroll
        for (int q = 0; q < 10; ++q) p[q] = 0.f;
        #pragma unroll
        for (int kk = 0; kk < 4; ++kk) {
            const int k = lane + kk * 64;
            const float hv = h2[r * 256 + k];
            #pragma unroll
            for (int q = 0; q < 10; ++q)
                p[q] = fmaf(hv, W3[q * 256 + k], p[q]);
        }
        #pragma unroll
        for (int q = 0; q < 10; ++q) {
            #pragma unroll
            for (int off = 32; off > 0; off >>= 1)
                p[q] += __shfl_down(p[q], off);
        }
        if (lane == 0) {
            float s[10], m = -1e30f;
            #pragma unroll
            for (int q = 0; q < 10; ++q) { s[q] = p[q] + b3[q]; m = fmaxf(m, s[q]); }
            float e[10], sum = 0.f;
            #pragma unroll
            for (int q = 0; q < 10; ++q) { e[q] = __expf(s[q] - m); sum += e[q]; }
            const float inv = 1.f / sum;
            #pragma unroll
            for (int q = 0; q < 10; ++q) {
                out[r * 10 + q] = e[q] * inv;
                out[5120 + r * 10 + q] = s[q];
            }
        }
        return;
    }

    float* __restrict__ S = out + 10240;
    int jt = 0;
    {
        int b = bid;
        while ((jt + 1) * (jt + 2) / 2 <= b) ++jt;
    }
    const int it = bid - jt * (jt + 1) / 2;
    const int r0 = it * 16, q0 = jt * 16;
    const bool diag = (it == jt);

    {
        half2v w;
        w.x = (_Float16)ws2[2 * t];
        w.y = (_Float16)ws2[2 * t + 1];
        wsh[t] = w;
    }
    #pragma unroll
    for (int i = 0; i < 4; ++i) {
        const int cidx = t + i * 256;
        const int row = cidx >> 6;
        const int c8  = cidx & 63;
        const float4 vr = *(const float4*)&A16[(r0 + row) * 512 + c8 * 8];
        const float4 vq = *(const float4*)&C16[(q0 + row) * 512 + c8 * 8];
        *(half8v*)&Rs[row][c8 * 8] = __builtin_bit_cast(half8v, vr);
        *(half8v*)&Qs[row][c8 * 8] = __builtin_bit_cast(half8v, vq);
    }
    __syncthreads();

    const int tx = t & 15, ty = t >> 4;
    const half2v* rp = (const half2v*)&Rs[ty][0];
    const half2v* qp = (const half2v*)&Qs[tx][0];
    const half2v z2 = {(_Float16)0, (_Float16)0};

    float a0 = 0.f;
    #pragma unroll 8
    for (int k2 = 0; k2 < 256; ++k2) {
        a0 = fdot2(__builtin_elementwise_max(rp[k2] + qp[k2], z2), wsh[k2], a0);
    }
    const float v = 1.f / (1.f + __expf(-(a0 + bs2[0])));

    Tt[ty][tx] = v;
    __syncthreads();

    if (diag) {
        const int r = r0 + ty, q = q0 + tx;
        const float o = (r < q) ? Tt[ty][tx] : (r > q ? Tt[tx][ty] : 0.f);
        S[r * 512 + q] = o;
    } else {
        S[(r0 + ty) * 512 + q0 + tx] = v;
        S[(q0 + ty) * 512 + r0 + tx] = Tt[tx][ty];
    }
}

extern "C" void kernel_launch(void* const* d_in, const int* in_sizes, int n_in,
                              void* d_out, int out_size, void* d_ws, size_t ws_size,
                              hipStream_t stream)
{
    const float* x   = (const float*)d_in[0];
    const float* W1  = (const float*)d_in[1];
    const float* b1  = (const float*)d_in[2];
    const float* g   = (const float*)d_in[3];
    const float* be  = (const float*)d_in[4];
    const float* mu  = (const float*)d_in[5];
    const float* va  = (const float*)d_in[6];
    const float* W2  = (const float*)d_in[7];
    const float* b2  = (const float*)d_in[8];
    const float* W3  = (const float*)d_in[9];
    const float* b3  = (const float*)d_in[10];
    const float* Wa  = (const float*)d_in[11];
    const float* Wb  = (const float*)d_in[12];
    const float* bs1 = (const float*)d_in[13];
    const float* ws2 = (const float*)d_in[14];
    const float* bs2 = (const float*)d_in[15];

    float* out = (float*)d_out;
    _Float16* h16 = (_Float16*)d_ws;               // 512*512 f16
    float* h2 = (float*)(h16 + 512 * 512);         // 512*256 f32
    _Float16* A16 = (_Float16*)(h2 + 512 * 256);   // 512*512 f16
    _Float16* C16 = A16 + 512 * 512;               // 512*512 f16

    fused3_mfma<<<dim3(16, 8, 3), 256, 0, stream>>>(x, W1, b1, g, be, mu, va,
                                                    Wa, bs1, Wb, h16, A16, C16);
    h2_mfma<<<dim3(8, 16), 256, 0, stream>>>(h16, W2, b2, h2);
    tail_kernel<<<656, 256, 0, stream>>>(h2, W3, b3, A16, C16, ws2, bs2, out);
}